// Round 2
// baseline (644.920 us; speedup 1.0000x reference)
//
#include <hip/hip_runtime.h>

#define NSCENE 8192
#define NAG 16
#define CIN 64
#define CH 128
#define R2f 64.0f

typedef unsigned short u16;

__device__ __forceinline__ float b2f(u16 v) {
    return __uint_as_float(((unsigned)v) << 16);
}
__device__ __forceinline__ u16 f2b(float f) {
    unsigned u = __float_as_uint(f);
    unsigned r = u + 0x7FFFu + ((u >> 16) & 1u);   // RNE
    return (u16)(r >> 16);
}

struct Smem {
    float xs[NAG][CIN];     // 4 KB
    float agg1[NAG][CIN];   // 4 KB
    float x1[NAG][CH];      // 8 KB
    float agg2[NAG][CH];    // 8 KB
    float x2[NAG][CH];      // 8 KB
    float h1[NAG][64];      // 4 KB
    float h2[NAG][32];      // 2 KB
    float px[NAG], py[NAG];
    unsigned mask[NAG];
};

struct Args {
    const void *x, *pos, *Wrel1, *brel1, *Wroot1, *Wrel2, *brel2, *Wroot2,
               *Wh1, *bh1, *Wh2, *bh2, *Wh3, *bh3;
    void* out;
};

template<bool F32>
__device__ __forceinline__ float LD(const void* p, int i) {
    if (F32) return ((const float*)p)[i];
    else     return b2f(((const u16*)p)[i]);
}

template<bool F32>
__device__ __forceinline__ void body(Smem& s, const Args& a) {
    const int t = threadIdx.x;
    const int scene = blockIdx.x;

    // ---- stage pos + x ----
    if (t < NAG) {
        s.px[t] = LD<F32>(a.pos, (scene * NAG + t) * 2 + 0);
        s.py[t] = LD<F32>(a.pos, (scene * NAG + t) * 2 + 1);
    }
    const int xbase = scene * NAG * CIN;
    for (int i = t; i < NAG * CIN; i += 256)
        s.xs[i >> 6][i & 63] = LD<F32>(a.x, xbase + i);
    __syncthreads();

    // ---- adjacency mask (radius graph, no self-loops) ----
    if (t < NAG) {
        unsigned m = 0;
        const float ax = s.px[t], ay = s.py[t];
        for (int j = 0; j < NAG; ++j) {
            const float dx = ax - s.px[j], dy = ay - s.py[j];
            if (dx * dx + dy * dy <= R2f && j != t) m |= (1u << j);
        }
        s.mask[t] = m;
    }
    __syncthreads();

    // ---- agg1 = adj @ x   [16,64] ----
    {
        const int ag = t >> 4;
        const int c = (t & 15) * 4;
        const unsigned m = s.mask[ag];
        float4 sm = {0.f, 0.f, 0.f, 0.f};
        for (int j = 0; j < NAG; ++j) {
            if (m & (1u << j)) {
                const float4 v = *(const float4*)&s.xs[j][c];
                sm.x += v.x; sm.y += v.y; sm.z += v.z; sm.w += v.w;
            }
        }
        *(float4*)&s.agg1[ag][c] = sm;
    }
    __syncthreads();

    // ---- layer 1: x1 = relu(agg1 @ Wrel1 + b1 + xs @ Wroot1)  [16,128] ----
    {
        const int o = t & 127;
        const int a0 = (t >> 7) * 8;
        float acc[8];
        #pragma unroll
        for (int i = 0; i < 8; ++i) acc[i] = 0.f;
        for (int c = 0; c < CIN; c += 4) {
            float wr[4], wt[4];
            #pragma unroll
            for (int k = 0; k < 4; ++k) {
                wr[k] = LD<F32>(a.Wrel1, (c + k) * CH + o);
                wt[k] = LD<F32>(a.Wroot1, (c + k) * CH + o);
            }
            #pragma unroll
            for (int i = 0; i < 8; ++i) {
                const float4 g  = *(const float4*)&s.agg1[a0 + i][c];
                const float4 xv = *(const float4*)&s.xs[a0 + i][c];
                acc[i] += g.x*wr[0] + g.y*wr[1] + g.z*wr[2] + g.w*wr[3]
                        + xv.x*wt[0] + xv.y*wt[1] + xv.z*wt[2] + xv.w*wt[3];
            }
        }
        const float b = LD<F32>(a.brel1, o);
        #pragma unroll
        for (int i = 0; i < 8; ++i) {
            const float v = acc[i] + b;
            s.x1[a0 + i][o] = v > 0.f ? v : 0.f;
        }
    }
    __syncthreads();

    // ---- agg2 = adj @ x1   [16,128] ----
    for (int e = t; e < NAG * CH / 4; e += 256) {
        const int ag = e >> 5;
        const int c = (e & 31) * 4;
        const unsigned m = s.mask[ag];
        float4 sm = {0.f, 0.f, 0.f, 0.f};
        for (int j = 0; j < NAG; ++j) {
            if (m & (1u << j)) {
                const float4 v = *(const float4*)&s.x1[j][c];
                sm.x += v.x; sm.y += v.y; sm.z += v.z; sm.w += v.w;
            }
        }
        *(float4*)&s.agg2[ag][c] = sm;
    }
    __syncthreads();

    // ---- layer 2: x2 = relu(agg2 @ Wrel2 + b2 + x1 @ Wroot2)  [16,128] ----
    {
        const int o = t & 127;
        const int a0 = (t >> 7) * 8;
        float acc[8];
        #pragma unroll
        for (int i = 0; i < 8; ++i) acc[i] = 0.f;
        for (int c = 0; c < CH; c += 4) {
            float wr[4], wt[4];
            #pragma unroll
            for (int k = 0; k < 4; ++k) {
                wr[k] = LD<F32>(a.Wrel2, (c + k) * CH + o);
                wt[k] = LD<F32>(a.Wroot2, (c + k) * CH + o);
            }
            #pragma unroll
            for (int i = 0; i < 8; ++i) {
                const float4 g  = *(const float4*)&s.agg2[a0 + i][c];
                const float4 xv = *(const float4*)&s.x1[a0 + i][c];
                acc[i] += g.x*wr[0] + g.y*wr[1] + g.z*wr[2] + g.w*wr[3]
                        + xv.x*wt[0] + xv.y*wt[1] + xv.z*wt[2] + xv.w*wt[3];
            }
        }
        const float b = LD<F32>(a.brel2, o);
        #pragma unroll
        for (int i = 0; i < 8; ++i) {
            const float v = acc[i] + b;
            s.x2[a0 + i][o] = v > 0.f ? v : 0.f;
        }
    }
    __syncthreads();

    // ---- MLP1: h1 = relu([x1|x2] @ Wh1 + bh1)  [16,64] ----
    {
        const int o = t & 63;
        const int a0 = (t >> 6) * 4;
        float acc[4] = {0.f, 0.f, 0.f, 0.f};
        for (int c = 0; c < CH; c += 4) {
            float w1[4], w2[4];
            #pragma unroll
            for (int k = 0; k < 4; ++k) {
                w1[k] = LD<F32>(a.Wh1, (c + k) * 64 + o);        // rows 0..127  (x1)
                w2[k] = LD<F32>(a.Wh1, (CH + c + k) * 64 + o);   // rows 128..255 (x2)
            }
            #pragma unroll
            for (int i = 0; i < 4; ++i) {
                const float4 v1 = *(const float4*)&s.x1[a0 + i][c];
                const float4 v2 = *(const float4*)&s.x2[a0 + i][c];
                acc[i] += v1.x*w1[0] + v1.y*w1[1] + v1.z*w1[2] + v1.w*w1[3]
                        + v2.x*w2[0] + v2.y*w2[1] + v2.z*w2[2] + v2.w*w2[3];
            }
        }
        const float b = LD<F32>(a.bh1, o);
        #pragma unroll
        for (int i = 0; i < 4; ++i) {
            const float v = acc[i] + b;
            s.h1[a0 + i][o] = v > 0.f ? v : 0.f;
        }
    }
    __syncthreads();

    // ---- MLP2: h2 = relu(h1 @ Wh2 + bh2)  [16,32] ----
    {
        const int o = t & 31;
        const int a0 = (t >> 5) * 2;
        float acc0 = 0.f, acc1 = 0.f;
        for (int c = 0; c < 64; c += 4) {
            float w[4];
            #pragma unroll
            for (int k = 0; k < 4; ++k) w[k] = LD<F32>(a.Wh2, (c + k) * 32 + o);
            const float4 u0 = *(const float4*)&s.h1[a0][c];
            const float4 u1 = *(const float4*)&s.h1[a0 + 1][c];
            acc0 += u0.x*w[0] + u0.y*w[1] + u0.z*w[2] + u0.w*w[3];
            acc1 += u1.x*w[0] + u1.y*w[1] + u1.z*w[2] + u1.w*w[3];
        }
        const float b = LD<F32>(a.bh2, o);
        const float v0 = acc0 + b; s.h2[a0][o]     = v0 > 0.f ? v0 : 0.f;
        const float v1 = acc1 + b; s.h2[a0 + 1][o] = v1 > 0.f ? v1 : 0.f;
    }
    __syncthreads();

    // ---- out = h2 @ Wh3 + bh3  [16,16] ----
    {
        const int ag = t >> 4;
        const int o = t & 15;
        float acc = LD<F32>(a.bh3, o);
        #pragma unroll
        for (int c = 0; c < 32; ++c)
            acc += s.h2[ag][c] * LD<F32>(a.Wh3, c * 16 + o);
        const int idx = scene * (NAG * 16) + ag * 16 + o;
        if (F32) ((float*)a.out)[idx] = acc;
        else     ((u16*)a.out)[idx] = f2b(acc);
    }
}

__global__ __launch_bounds__(256) void gnn_fused(Args a) {
    __shared__ Smem s;

    // ---- dtype sniff on x (uniform across all threads/blocks, every call) ----
    // If x is bf16: even u16s are genuine N(0,1) values -> |v| < 64 always.
    // If x is f32: even u16s are low mantissa bits -> exponent field uniform,
    // P(|v|<64) ~ 0.52 per sample; P(>=28 of 32) is negligible.
    const u16* xu = (const u16*)a.x;
    int good = 0;
    #pragma unroll
    for (int i = 0; i < 32; ++i) {
        const unsigned e = (((unsigned)xu[2 * i]) >> 7) & 0xFFu;  // bf16 exponent field
        good += (e < 133u) ? 1 : 0;                               // |v| < 64 (incl. 0/denorm)
    }
    if (good >= 28) body<false>(s, a);   // bf16 path
    else            body<true>(s, a);    // f32 path
}

extern "C" void kernel_launch(void* const* d_in, const int* in_sizes, int n_in,
                              void* d_out, int out_size, void* d_ws, size_t ws_size,
                              hipStream_t stream) {
    Args a;
    a.x      = d_in[0];
    a.pos    = d_in[1];
    a.Wrel1  = d_in[2];
    a.brel1  = d_in[3];
    a.Wroot1 = d_in[4];
    a.Wrel2  = d_in[5];
    a.brel2  = d_in[6];
    a.Wroot2 = d_in[7];
    a.Wh1    = d_in[8];
    a.bh1    = d_in[9];
    a.Wh2    = d_in[10];
    a.bh2    = d_in[11];
    a.Wh3    = d_in[12];
    a.bh3    = d_in[13];
    a.out    = d_out;

    gnn_fused<<<NSCENE, 256, 0, stream>>>(a);
}

// Round 3
// 146.088 us; speedup vs baseline: 4.4146x; 4.4146x over previous
//
#include <hip/hip_runtime.h>

#define NSCENE 8192
#define NAG 16
#define R2f 64.0f

typedef unsigned short u16;
typedef __attribute__((ext_vector_type(8))) short short8;
typedef __attribute__((ext_vector_type(4))) float f32x4;

// blob offsets in u16 units inside d_ws
#define OFF_B1 0        // [Wroot1;Wrel1]  K=128 N=128  S=4 T=8  -> 16384
#define OFF_B2 16384    // [Wroot2;Wrel2]  K=256 N=128  S=8 T=8  -> 32768
#define OFF_H1 49152    // Wh1             K=256 N=64   S=8 T=4  -> 16384
#define OFF_H2 65536    // Wh2             K=64  N=32   S=2 T=2  -> 2048
#define OFF_H3 67584    // Wh3             K=32  N=16   S=1 T=1  -> 512
#define SWZ_UNITS 8512  // total fragment-lane units (×8 u16 each)

__device__ __forceinline__ u16 f2b(float f) {
    unsigned u = __float_as_uint(f);
    unsigned r = u + 0x7FFFu + ((u >> 16) & 1u);   // RNE
    return (u16)(r >> 16);
}

// ---------------- weight pre-swizzle: W[K][N] f32 -> B-fragment order bf16 ---
// unit u = (s, t, lane); element j: k = s*32 + (lane>>4)*8 + j, n = t*16 + (lane&15)
__global__ __launch_bounds__(256) void swizzle_w(
    const float* __restrict__ Wrel1, const float* __restrict__ Wroot1,
    const float* __restrict__ Wrel2, const float* __restrict__ Wroot2,
    const float* __restrict__ Wh1,  const float* __restrict__ Wh2,
    const float* __restrict__ Wh3,  u16* __restrict__ ws)
{
    const int u = blockIdx.x * 256 + threadIdx.x;
    if (u >= SWZ_UNITS) return;

    int v, T, N, ksplit;
    const float *W, *W2;
    u16* dst;
    if (u < 2048)      { v = u;        T = 8; N = 128; ksplit = 64;  W = Wroot1; W2 = Wrel1; dst = ws + OFF_B1 + v * 8; }
    else if (u < 6144) { v = u - 2048; T = 8; N = 128; ksplit = 128; W = Wroot2; W2 = Wrel2; dst = ws + OFF_B2 + v * 8; }
    else if (u < 8192) { v = u - 6144; T = 4; N = 64;  ksplit = 1 << 30; W = Wh1; W2 = Wh1; dst = ws + OFF_H1 + v * 8; }
    else if (u < 8448) { v = u - 8192; T = 2; N = 32;  ksplit = 1 << 30; W = Wh2; W2 = Wh2; dst = ws + OFF_H2 + v * 8; }
    else               { v = u - 8448; T = 1; N = 16;  ksplit = 1 << 30; W = Wh3; W2 = Wh3; dst = ws + OFF_H3 + v * 8; }

    const int lane = v & 63;
    const int t = (v >> 6) % T;
    const int s = (v >> 6) / T;
    const int n = t * 16 + (lane & 15);
    const int k0 = s * 32 + (lane >> 4) * 8;
    #pragma unroll
    for (int j = 0; j < 8; ++j) {
        const int k = k0 + j;
        const float val = (k < ksplit) ? W[k * N + n] : W2[(k - ksplit) * N + n];
        dst[j] = f2b(val);
    }
}

// ---------------- main fused kernel: one block per scene ---------------------
__device__ __forceinline__ void unpack2(unsigned w, float& a, float& b) {
    a = __uint_as_float(w << 16);          // low u16 -> float
    b = __uint_as_float(w & 0xFFFF0000u);  // high u16 -> float
}

__global__ __launch_bounds__(256) void gnn_mfma(
    const float* __restrict__ x, const float* __restrict__ pos,
    const float* __restrict__ brel1, const float* __restrict__ brel2,
    const float* __restrict__ bh1,  const float* __restrict__ bh2,
    const float* __restrict__ bh3,
    const u16* __restrict__ ws, float* __restrict__ out)
{
    // row strides chosen so every row base and fragment offset is 16B aligned
    __shared__ __align__(16) u16 XA[16 * 136];   // cols 0..63 x(bf16), 64..127 agg1
    __shared__ __align__(16) u16 X12[16 * 272];  // cols 0..127 x1, 128..255 agg2
    __shared__ __align__(16) u16 X2s[16 * 136];  // cols 0..127 x2
    __shared__ __align__(16) u16 H1s[16 * 72];   // cols 0..63
    __shared__ __align__(16) u16 H2s[16 * 48];   // cols 0..31
    __shared__ unsigned mask[NAG];

    const int t = threadIdx.x;
    const int scene = blockIdx.x;
    const int wv = t >> 6;
    const int lane = t & 63;
    const int mrow = lane & 15;
    const int q = lane >> 4;

    // ---- stage x (f32 -> bf16) and adjacency mask ----
    {
        const int i0 = t * 4;                       // 0..1020
        const float4 v = *(const float4*)(x + scene * (NAG * 64) + i0);
        u16* d = &XA[(i0 >> 6) * 136 + (i0 & 63)];
        d[0] = f2b(v.x); d[1] = f2b(v.y); d[2] = f2b(v.z); d[3] = f2b(v.w);
    }
    if (t < NAG) {
        const float* pp = pos + scene * (NAG * 2);
        const float ax = pp[2 * t], ay = pp[2 * t + 1];
        unsigned m = 0;
        for (int j = 0; j < NAG; ++j) {
            const float dx = ax - pp[2 * j], dy = ay - pp[2 * j + 1];
            if (dx * dx + dy * dy <= R2f && j != t) m |= (1u << j);
        }
        mask[t] = m;
    }
    __syncthreads();

    // ---- agg1 = adj @ x  -> XA cols 64..127 (bf16) ----
    {
        const int a = t >> 4, c0 = (t & 15) * 4;
        const unsigned m = mask[a];
        float s0 = 0.f, s1 = 0.f, s2 = 0.f, s3 = 0.f;
        for (int j = 0; j < NAG; ++j) {
            const unsigned* p = (const unsigned*)&XA[j * 136 + c0];
            float f0, f1, f2, f3;
            unpack2(p[0], f0, f1); unpack2(p[1], f2, f3);
            const bool on = (m >> j) & 1;
            s0 += on ? f0 : 0.f; s1 += on ? f1 : 0.f;
            s2 += on ? f2 : 0.f; s3 += on ? f3 : 0.f;
        }
        u16* d = &XA[a * 136 + 64 + c0];
        d[0] = f2b(s0); d[1] = f2b(s1); d[2] = f2b(s2); d[3] = f2b(s3);
    }
    __syncthreads();

    // ---- layer1: x1 = relu([x|agg1] @ [Wroot1;Wrel1] + brel1) ----
    {
        const float bias0 = brel1[wv * 32 + mrow];
        const float bias1 = brel1[wv * 32 + 16 + mrow];
        f32x4 acc0 = {0.f, 0.f, 0.f, 0.f}, acc1 = acc0;
        #pragma unroll
        for (int s = 0; s < 4; ++s) {
            const short8 a = *(const short8*)&XA[mrow * 136 + s * 32 + q * 8];
            const short8 b0 = *(const short8*)&ws[OFF_B1 + ((s * 8 + 2 * wv) * 64 + lane) * 8];
            const short8 b1 = *(const short8*)&ws[OFF_B1 + ((s * 8 + 2 * wv + 1) * 64 + lane) * 8];
            acc0 = __builtin_amdgcn_mfma_f32_16x16x32_bf16(a, b0, acc0, 0, 0, 0);
            acc1 = __builtin_amdgcn_mfma_f32_16x16x32_bf16(a, b1, acc1, 0, 0, 0);
        }
        #pragma unroll
        for (int r = 0; r < 4; ++r) {
            const int row = q * 4 + r;
            float v0 = acc0[r] + bias0; v0 = v0 > 0.f ? v0 : 0.f;
            float v1 = acc1[r] + bias1; v1 = v1 > 0.f ? v1 : 0.f;
            X12[row * 272 + wv * 32 + mrow] = f2b(v0);
            X12[row * 272 + wv * 32 + 16 + mrow] = f2b(v1);
        }
    }
    __syncthreads();

    // ---- agg2 = adj @ x1 -> X12 cols 128..255 ----
    {
        const int a = t >> 4, c0 = (t & 15) * 8;
        const unsigned m = mask[a];
        float s0=0.f,s1=0.f,s2=0.f,s3=0.f,s4=0.f,s5=0.f,s6=0.f,s7=0.f;
        for (int j = 0; j < NAG; ++j) {
            const unsigned* p = (const unsigned*)&X12[j * 272 + c0];
            float f0,f1,f2,f3,f4,f5,f6,f7;
            unpack2(p[0], f0, f1); unpack2(p[1], f2, f3);
            unpack2(p[2], f4, f5); unpack2(p[3], f6, f7);
            const bool on = (m >> j) & 1;
            s0 += on ? f0 : 0.f; s1 += on ? f1 : 0.f; s2 += on ? f2 : 0.f; s3 += on ? f3 : 0.f;
            s4 += on ? f4 : 0.f; s5 += on ? f5 : 0.f; s6 += on ? f6 : 0.f; s7 += on ? f7 : 0.f;
        }
        u16* d = &X12[a * 272 + 128 + c0];
        d[0]=f2b(s0); d[1]=f2b(s1); d[2]=f2b(s2); d[3]=f2b(s3);
        d[4]=f2b(s4); d[5]=f2b(s5); d[6]=f2b(s6); d[7]=f2b(s7);
    }
    __syncthreads();

    // ---- layer2: x2 = relu([x1|agg2] @ [Wroot2;Wrel2] + brel2) ----
    {
        const float bias0 = brel2[wv * 32 + mrow];
        const float bias1 = brel2[wv * 32 + 16 + mrow];
        f32x4 acc0 = {0.f, 0.f, 0.f, 0.f}, acc1 = acc0;
        #pragma unroll
        for (int s = 0; s < 8; ++s) {
            const short8 a = *(const short8*)&X12[mrow * 272 + s * 32 + q * 8];
            const short8 b0 = *(const short8*)&ws[OFF_B2 + ((s * 8 + 2 * wv) * 64 + lane) * 8];
            const short8 b1 = *(const short8*)&ws[OFF_B2 + ((s * 8 + 2 * wv + 1) * 64 + lane) * 8];
            acc0 = __builtin_amdgcn_mfma_f32_16x16x32_bf16(a, b0, acc0, 0, 0, 0);
            acc1 = __builtin_amdgcn_mfma_f32_16x16x32_bf16(a, b1, acc1, 0, 0, 0);
        }
        #pragma unroll
        for (int r = 0; r < 4; ++r) {
            const int row = q * 4 + r;
            float v0 = acc0[r] + bias0; v0 = v0 > 0.f ? v0 : 0.f;
            float v1 = acc1[r] + bias1; v1 = v1 > 0.f ? v1 : 0.f;
            X2s[row * 136 + wv * 32 + mrow] = f2b(v0);
            X2s[row * 136 + wv * 32 + 16 + mrow] = f2b(v1);
        }
    }
    __syncthreads();

    // ---- MLP1: h1 = relu([x1|x2] @ Wh1 + bh1)  N=64, wave wv -> tile wv ----
    {
        const float bias = bh1[wv * 16 + mrow];
        f32x4 acc = {0.f, 0.f, 0.f, 0.f};
        #pragma unroll
        for (int s = 0; s < 8; ++s) {
            const short8 a = (s < 4)
                ? *(const short8*)&X12[mrow * 272 + s * 32 + q * 8]
                : *(const short8*)&X2s[mrow * 136 + (s - 4) * 32 + q * 8];
            const short8 b = *(const short8*)&ws[OFF_H1 + ((s * 4 + wv) * 64 + lane) * 8];
            acc = __builtin_amdgcn_mfma_f32_16x16x32_bf16(a, b, acc, 0, 0, 0);
        }
        #pragma unroll
        for (int r = 0; r < 4; ++r) {
            float v = acc[r] + bias; v = v > 0.f ? v : 0.f;
            H1s[(q * 4 + r) * 72 + wv * 16 + mrow] = f2b(v);
        }
    }
    __syncthreads();

    // ---- MLP2: h2 = relu(h1 @ Wh2 + bh2)  N=32, waves 0,1 ----
    if (wv < 2) {
        const float bias = bh2[wv * 16 + mrow];
        f32x4 acc = {0.f, 0.f, 0.f, 0.f};
        #pragma unroll
        for (int s = 0; s < 2; ++s) {
            const short8 a = *(const short8*)&H1s[mrow * 72 + s * 32 + q * 8];
            const short8 b = *(const short8*)&ws[OFF_H2 + ((s * 2 + wv) * 64 + lane) * 8];
            acc = __builtin_amdgcn_mfma_f32_16x16x32_bf16(a, b, acc, 0, 0, 0);
        }
        #pragma unroll
        for (int r = 0; r < 4; ++r) {
            float v = acc[r] + bias; v = v > 0.f ? v : 0.f;
            H2s[(q * 4 + r) * 48 + wv * 16 + mrow] = f2b(v);
        }
    }
    __syncthreads();

    // ---- out = h2 @ Wh3 + bh3  [16,16], wave 0, f32 store ----
    if (wv == 0) {
        const float bias = bh3[mrow];
        f32x4 acc = {0.f, 0.f, 0.f, 0.f};
        const short8 a = *(const short8*)&H2s[mrow * 48 + q * 8];
        const short8 b = *(const short8*)&ws[OFF_H3 + lane * 8];
        acc = __builtin_amdgcn_mfma_f32_16x16x32_bf16(a, b, acc, 0, 0, 0);
        float* o = out + scene * (NAG * 16);
        #pragma unroll
        for (int r = 0; r < 4; ++r)
            o[(q * 4 + r) * 16 + mrow] = acc[r] + bias;
    }
}

extern "C" void kernel_launch(void* const* d_in, const int* in_sizes, int n_in,
                              void* d_out, int out_size, void* d_ws, size_t ws_size,
                              hipStream_t stream) {
    const float* x      = (const float*)d_in[0];
    const float* pos    = (const float*)d_in[1];
    const float* Wrel1  = (const float*)d_in[2];
    const float* brel1  = (const float*)d_in[3];
    const float* Wroot1 = (const float*)d_in[4];
    const float* Wrel2  = (const float*)d_in[5];
    const float* brel2  = (const float*)d_in[6];
    const float* Wroot2 = (const float*)d_in[7];
    const float* Wh1    = (const float*)d_in[8];
    const float* bh1    = (const float*)d_in[9];
    const float* Wh2    = (const float*)d_in[10];
    const float* bh2    = (const float*)d_in[11];
    const float* Wh3    = (const float*)d_in[12];
    const float* bh3    = (const float*)d_in[13];
    u16* ws = (u16*)d_ws;

    swizzle_w<<<(SWZ_UNITS + 255) / 256, 256, 0, stream>>>(
        Wrel1, Wroot1, Wrel2, Wroot2, Wh1, Wh2, Wh3, ws);
    gnn_mfma<<<NSCENE, 256, 0, stream>>>(
        x, pos, brel1, brel2, bh1, bh2, bh3, ws, (float*)d_out);
}

// Round 4
// 144.163 us; speedup vs baseline: 4.4736x; 1.0134x over previous
//
#include <hip/hip_runtime.h>

#define NAG 16
#define SPB 16      // scenes per block
#define NBLK 512    // 512 * 16 = 8192 scenes
#define R2f 64.0f

typedef unsigned short u16;
typedef __attribute__((ext_vector_type(8))) short short8;
typedef __attribute__((ext_vector_type(4))) float f32x4;

#define MFMA(a, b, c) __builtin_amdgcn_mfma_f32_16x16x32_bf16(a, b, c, 0, 0, 0)

__device__ __forceinline__ u16 f2b(float f) {
    unsigned u = __float_as_uint(f);
    unsigned r = u + 0x7FFFu + ((u >> 16) & 1u);   // RNE
    return (u16)(r >> 16);
}

// A-fragment of W^T for output-channel tile `tile`, K-step `s` (32 input chans):
// element j <-> k = s*32 + q*8 + j, m = tile*16 + mrow; value = W[k][m] (W is [K][N] row-major)
__device__ __forceinline__ short8 load_wfrag(const float* __restrict__ W, int N,
                                             int tile, int s, int q, int mrow) {
    const float* p = W + (size_t)(s * 32 + q * 8) * N + tile * 16 + mrow;
    union { short8 v; unsigned u[4]; } r;
    #pragma unroll
    for (int jj = 0; jj < 4; ++jj) {
        const float f0 = p[(2 * jj) * N];
        const float f1 = p[(2 * jj + 1) * N];
        r.u[jj] = (unsigned)f2b(f0) | ((unsigned)f2b(f1) << 16);
    }
    return r.v;
}

// adjacency B-fragment: B[k][i], i = lane&15, k = q*8+j; adj[k][i] = bit k of mask[i]
// (adj symmetric). k >= 16 -> bits shift out -> exact 0.
__device__ __forceinline__ short8 make_adjB(unsigned m, int q) {
    union { short8 v; unsigned u[4]; } r;
    #pragma unroll
    for (int jj = 0; jj < 4; ++jj) {
        const int k0 = q * 8 + 2 * jj;              // <= 30
        const unsigned lo = ((m >> k0) & 1u) ? 0x3F80u : 0u;        // bf16 1.0
        const unsigned hi = ((m >> (k0 + 1)) & 1u) ? 0x3F80u : 0u;
        r.u[jj] = lo | (hi << 16);
    }
    return r.v;
}

__device__ __forceinline__ void relu_store4(u16* d, f32x4 a) {
    const unsigned p0 = (unsigned)f2b(fmaxf(a[0], 0.f)) | ((unsigned)f2b(fmaxf(a[1], 0.f)) << 16);
    const unsigned p1 = (unsigned)f2b(fmaxf(a[2], 0.f)) | ((unsigned)f2b(fmaxf(a[3], 0.f)) << 16);
    uint2 u; u.x = p0; u.y = p1;
    *(uint2*)d = u;   // 8B-aligned by construction at call sites
}

__global__ __launch_bounds__(256, 2) void gnn_fused2(
    const float* __restrict__ x, const float* __restrict__ pos,
    const float* __restrict__ Wrel1, const float* __restrict__ brel1,
    const float* __restrict__ Wroot1,
    const float* __restrict__ Wrel2, const float* __restrict__ brel2,
    const float* __restrict__ Wroot2,
    const float* __restrict__ Wh1, const float* __restrict__ bh1,
    const float* __restrict__ Wh2, const float* __restrict__ bh2,
    const float* __restrict__ Wh3, const float* __restrict__ bh3,
    float* __restrict__ out)
{
    // padded row strides: +8 u16 (16B) keeps b128 rows on distinct bank groups
    __shared__ __align__(16) u16 xb[16 * 72];     // x   [agent][ch0..63]
    __shared__ __align__(16) u16 yT[128 * 40];    // y^T [channel][agent0..15 | 16..31 = zero pad]
    __shared__ __align__(16) u16 x1b[16 * 136];   // x1  [agent][ch0..127]
    __shared__ __align__(16) u16 x2b[16 * 136];   // x2
    __shared__ __align__(16) u16 h1b[16 * 72];    // h1  [agent][ch0..63]
    __shared__ __align__(16) u16 h2b[16 * 40];    // h2  [agent][ch0..31]
    __shared__ unsigned mask[NAG];

    const int t = threadIdx.x;
    const int wv = t >> 6;
    const int lane = t & 63;
    const int mrow = lane & 15;
    const int q = lane >> 4;
    const int t0 = 2 * wv, t1 = 2 * wv + 1;       // output-channel tiles per wave

    // zero yT agent-pad (cols 16..31) once; never overwritten (avoids 0*NaN)
    for (int i = t; i < 128 * 16; i += 256)
        yT[(i >> 4) * 40 + 16 + (i & 15)] = 0;

    // ---- all weight fragments -> registers (once per block, reused SPB times) ----
    short8 wr1[2][2], wo1[2][2], wr2[2][4], wo2[2][4], wh1f[8], wh2f[2], wh3f;
    #pragma unroll
    for (int i = 0; i < 2; ++i) {
        #pragma unroll
        for (int s = 0; s < 2; ++s) {
            wr1[i][s] = load_wfrag(Wrel1, 128, t0 + i, s, q, mrow);
            wo1[i][s] = load_wfrag(Wroot1, 128, t0 + i, s, q, mrow);
        }
        #pragma unroll
        for (int s = 0; s < 4; ++s) {
            wr2[i][s] = load_wfrag(Wrel2, 128, t0 + i, s, q, mrow);
            wo2[i][s] = load_wfrag(Wroot2, 128, t0 + i, s, q, mrow);
        }
    }
    #pragma unroll
    for (int s = 0; s < 8; ++s) wh1f[s] = load_wfrag(Wh1, 64, wv, s, q, mrow);
    #pragma unroll
    for (int s = 0; s < 2; ++s) wh2f[s] = load_wfrag(Wh2, 32, wv & 1, s, q, mrow);
    wh3f = load_wfrag(Wh3, 16, 0, 0, q, mrow);

    // biases (acc row = q*4+r -> channel tile*16 + q*4 + r)
    const float4 br1a = *(const float4*)(brel1 + t0 * 16 + q * 4);
    const float4 br1b = *(const float4*)(brel1 + t1 * 16 + q * 4);
    const float4 br2a = *(const float4*)(brel2 + t0 * 16 + q * 4);
    const float4 br2b = *(const float4*)(brel2 + t1 * 16 + q * 4);
    const float4 bb1  = *(const float4*)(bh1 + wv * 16 + q * 4);
    const float4 bb2  = *(const float4*)(bh2 + (wv & 1) * 16 + q * 4);
    const float4 bb3  = *(const float4*)(bh3 + q * 4);

    #pragma unroll 1
    for (int g = 0; g < SPB; ++g) {
        const size_t scene = (size_t)blockIdx.x * SPB + g;

        // ---- S0: stage x (f32 -> bf16) + adjacency masks ----
        {
            const int i0 = t * 4;
            const float4 v = *(const float4*)(x + scene * (NAG * 64) + i0);
            const unsigned p0 = (unsigned)f2b(v.x) | ((unsigned)f2b(v.y) << 16);
            const unsigned p1 = (unsigned)f2b(v.z) | ((unsigned)f2b(v.w) << 16);
            uint2 u; u.x = p0; u.y = p1;
            *(uint2*)&xb[(i0 >> 6) * 72 + (i0 & 63)] = u;
        }
        if (t < NAG) {
            const float* pp = pos + scene * (NAG * 2);
            const float ax = pp[2 * t], ay = pp[2 * t + 1];
            unsigned m = 0;
            for (int j = 0; j < NAG; ++j) {
                const float dx = ax - pp[2 * j], dy = ay - pp[2 * j + 1];
                if (dx * dx + dy * dy <= R2f && j != t) m |= (1u << j);
            }
            mask[t] = m;
        }
        __syncthreads();

        const short8 adjB = make_adjB(mask[mrow], q);   // reused by S2 and S4

        // ---- S1: y1^T = Wrel1^T @ x  -> yT ----
        {
            f32x4 a0 = {0.f, 0.f, 0.f, 0.f}, a1 = a0;
            #pragma unroll
            for (int s = 0; s < 2; ++s) {
                const short8 b = *(const short8*)&xb[mrow * 72 + s * 32 + q * 8];
                a0 = MFMA(wr1[0][s], b, a0);
                a1 = MFMA(wr1[1][s], b, a1);
            }
            #pragma unroll
            for (int r = 0; r < 4; ++r) {
                yT[(t0 * 16 + q * 4 + r) * 40 + mrow] = f2b(a0[r]);
                yT[(t1 * 16 + q * 4 + r) * 40 + mrow] = f2b(a1[r]);
            }
        }
        __syncthreads();

        // ---- S2: x1 = relu(adj@y1 + Wroot1^T@x + b1) -> x1b [agent][ch] ----
        {
            f32x4 a0 = {br1a.x, br1a.y, br1a.z, br1a.w};
            f32x4 a1 = {br1b.x, br1b.y, br1b.z, br1b.w};
            const short8 ya0 = *(const short8*)&yT[(t0 * 16 + mrow) * 40 + q * 8];
            const short8 ya1 = *(const short8*)&yT[(t1 * 16 + mrow) * 40 + q * 8];
            a0 = MFMA(ya0, adjB, a0);
            a1 = MFMA(ya1, adjB, a1);
            #pragma unroll
            for (int s = 0; s < 2; ++s) {
                const short8 b = *(const short8*)&xb[mrow * 72 + s * 32 + q * 8];
                a0 = MFMA(wo1[0][s], b, a0);
                a1 = MFMA(wo1[1][s], b, a1);
            }
            relu_store4(&x1b[mrow * 136 + t0 * 16 + q * 4], a0);
            relu_store4(&x1b[mrow * 136 + t1 * 16 + q * 4], a1);
        }
        __syncthreads();

        // ---- S3: y2^T = Wrel2^T @ x1 -> yT ----
        {
            f32x4 a0 = {0.f, 0.f, 0.f, 0.f}, a1 = a0;
            #pragma unroll
            for (int s = 0; s < 4; ++s) {
                const short8 b = *(const short8*)&x1b[mrow * 136 + s * 32 + q * 8];
                a0 = MFMA(wr2[0][s], b, a0);
                a1 = MFMA(wr2[1][s], b, a1);
            }
            #pragma unroll
            for (int r = 0; r < 4; ++r) {
                yT[(t0 * 16 + q * 4 + r) * 40 + mrow] = f2b(a0[r]);
                yT[(t1 * 16 + q * 4 + r) * 40 + mrow] = f2b(a1[r]);
            }
        }
        __syncthreads();

        // ---- S4: x2 = relu(adj@y2 + Wroot2^T@x1 + b2) -> x2b ----
        {
            f32x4 a0 = {br2a.x, br2a.y, br2a.z, br2a.w};
            f32x4 a1 = {br2b.x, br2b.y, br2b.z, br2b.w};
            const short8 ya0 = *(const short8*)&yT[(t0 * 16 + mrow) * 40 + q * 8];
            const short8 ya1 = *(const short8*)&yT[(t1 * 16 + mrow) * 40 + q * 8];
            a0 = MFMA(ya0, adjB, a0);
            a1 = MFMA(ya1, adjB, a1);
            #pragma unroll
            for (int s = 0; s < 4; ++s) {
                const short8 b = *(const short8*)&x1b[mrow * 136 + s * 32 + q * 8];
                a0 = MFMA(wo2[0][s], b, a0);
                a1 = MFMA(wo2[1][s], b, a1);
            }
            relu_store4(&x2b[mrow * 136 + t0 * 16 + q * 4], a0);
            relu_store4(&x2b[mrow * 136 + t1 * 16 + q * 4], a1);
        }
        __syncthreads();

        // ---- S5: h1 = relu(Wh1^T @ [x1|x2] + bh1), tile = wv -> h1b ----
        {
            f32x4 a = {bb1.x, bb1.y, bb1.z, bb1.w};
            #pragma unroll
            for (int s = 0; s < 8; ++s) {
                const short8 b = (s < 4)
                    ? *(const short8*)&x1b[mrow * 136 + s * 32 + q * 8]
                    : *(const short8*)&x2b[mrow * 136 + (s - 4) * 32 + q * 8];
                a = MFMA(wh1f[s], b, a);
            }
            relu_store4(&h1b[mrow * 72 + wv * 16 + q * 4], a);
        }
        __syncthreads();

        // ---- S6: h2 = relu(Wh2^T @ h1 + bh2), waves 0,1 -> h2b ----
        if (wv < 2) {
            f32x4 a = {bb2.x, bb2.y, bb2.z, bb2.w};
            #pragma unroll
            for (int s = 0; s < 2; ++s) {
                const short8 b = *(const short8*)&h1b[mrow * 72 + s * 32 + q * 8];
                a = MFMA(wh2f[s], b, a);
            }
            relu_store4(&h2b[mrow * 40 + wv * 16 + q * 4], a);
        }
        __syncthreads();

        // ---- S7: out = Wh3^T @ h2 + bh3, wave 0, f32 coalesced store ----
        if (wv == 0) {
            f32x4 a = {bb3.x, bb3.y, bb3.z, bb3.w};
            const short8 b = *(const short8*)&h2b[mrow * 40 + q * 8];
            a = MFMA(wh3f, b, a);
            float4 o; o.x = a[0]; o.y = a[1]; o.z = a[2]; o.w = a[3];
            *(float4*)(out + scene * (NAG * 16) + mrow * 16 + q * 4) = o;
        }
        // no barrier: next S0's barrier orders h2b reuse (wave 0 must pass it first)
    }
}

extern "C" void kernel_launch(void* const* d_in, const int* in_sizes, int n_in,
                              void* d_out, int out_size, void* d_ws, size_t ws_size,
                              hipStream_t stream) {
    const float* x      = (const float*)d_in[0];
    const float* pos    = (const float*)d_in[1];
    const float* Wrel1  = (const float*)d_in[2];
    const float* brel1  = (const float*)d_in[3];
    const float* Wroot1 = (const float*)d_in[4];
    const float* Wrel2  = (const float*)d_in[5];
    const float* brel2  = (const float*)d_in[6];
    const float* Wroot2 = (const float*)d_in[7];
    const float* Wh1    = (const float*)d_in[8];
    const float* bh1    = (const float*)d_in[9];
    const float* Wh2    = (const float*)d_in[10];
    const float* bh2    = (const float*)d_in[11];
    const float* Wh3    = (const float*)d_in[12];
    const float* bh3    = (const float*)d_in[13];

    gnn_fused2<<<NBLK, 256, 0, stream>>>(
        x, pos, Wrel1, brel1, Wroot1, Wrel2, brel2, Wroot2,
        Wh1, bh1, Wh2, bh2, Wh3, bh3, (float*)d_out);
}